// Round 6
// baseline (87.982 us; speedup 1.0000x reference)
//
#include <hip/hip_runtime.h>
#include <hip/hip_bf16.h>

#define NPTS 262144
#define HID  20
#define NMID 8

typedef float f32x16 __attribute__((ext_vector_type(16)));
typedef short short8 __attribute__((ext_vector_type(8)));
typedef unsigned int u32;

__device__ __forceinline__ u32 bf16_bits(float f) {
    u32 u = __builtin_bit_cast(u32, f);
    return (u + 0x7FFFu + ((u >> 16) & 1u)) >> 16;   // RNE (host-side staging use)
}

// packed bf16 pair via the library converter (no inline asm, no bit_cast of bf16 types)
__device__ __forceinline__ u32 pkrn(float a, float b) {
    __hip_bfloat162 t = __float22bfloat162_rn(make_float2(a, b));  // x=lo, y=hi
    u32 r; __builtin_memcpy(&r, &t, 4); return r;
}

__device__ __forceinline__ u32 xor32(u32 a) {
    return (u32)__shfl_xor((int)a, 32);   // proven cross-half exchange (R3/R5)
}

__device__ __forceinline__ float flo(u32 c) { return __builtin_bit_cast(float, c << 16); }
__device__ __forceinline__ float fhi(u32 c) { return __builtin_bit_cast(float, c & 0xFFFF0000u); }

__device__ __forceinline__ short8 mk_frag(const u32* d, int o) {
    uint4 v = make_uint4(d[o + 0], d[o + 1], d[o + 2], d[o + 3]);
    return __builtin_bit_cast(short8, v);
}

// C/D regs 0..11 (rows 0..23) -> B frags (hi + lo residual), bf16.
// s=0 words need the cross-half exchange; s=1 frag's hi-lane elements are
// k=24..31 where A columns are zero -> don't-care (finite). Verified by R5 pass.
__device__ __forceinline__ void build_frags(const float* v, int hi, u32 bias,
                                            u32* bh, u32* bl) {
    u32 h01 = pkrn(v[0], v[1]),   h23 = pkrn(v[2], v[3]);
    u32 h45 = pkrn(v[4], v[5]),   h67 = pkrn(v[6], v[7]);
    u32 h89 = pkrn(v[8], v[9]),   hAB = pkrn(v[10], v[11]);
    u32 l01 = pkrn(v[0] - flo(h01), v[1] - fhi(h01));
    u32 l23 = pkrn(v[2] - flo(h23), v[3] - fhi(h23));
    u32 l45 = pkrn(v[4] - flo(h45), v[5] - fhi(h45));
    u32 l67 = pkrn(v[6] - flo(h67), v[7] - fhi(h67));
    u32 l89 = pkrn(v[8] - flo(h89), v[9] - fhi(h89));
    u32 lAB = pkrn(v[10] - flo(hAB), v[11] - fhi(hAB));
    u32 h01x = xor32(h01), h23x = xor32(h23), h45x = xor32(h45), h67x = xor32(h67);
    u32 l01x = xor32(l01), l23x = xor32(l23), l45x = xor32(l45), l67x = xor32(l67);
    bh[0] = hi ? h45x : h01;  bh[1] = hi ? h67x : h23;
    bh[2] = hi ? h45  : h01x; bh[3] = hi ? h67  : h23x;
    bh[4] = h89; bh[5] = hAB; bh[6] = bias; bh[7] = 0u;
    bl[0] = hi ? l45x : l01;  bl[1] = hi ? l67x : l23;
    bl[2] = hi ? l45  : l01x; bl[3] = hi ? l67  : l23x;
    bl[4] = l89; bl[5] = lAB; bl[6] = 0u;   bl[7] = 0u;
}

#define MF(A, D, O, C) __builtin_amdgcn_mfma_f32_32x32x16_bf16(A, mk_frag(D, O), C, 0, 0, 0)

__launch_bounds__(256, 2)
__global__ void pde_mfma_kernel(const float* __restrict__ x,
                                const float* __restrict__ W_in,
                                const float* __restrict__ b_in,
                                const float* __restrict__ W_mid,
                                const float* __restrict__ b_mid,
                                const float* __restrict__ W_out,
                                const float* __restrict__ b_out,
                                float* __restrict__ out) {
    // A-frags: [layer][part: hi s=0, hi s=1, lo s=0, lo s=1][lane][8]; bias as col k=20.
    __shared__ short sWf[NMID * 4 * 64 * 8];   // 32 KB
    __shared__ float sIn[2 * 16 * 4];

    const int tid = threadIdx.x;

    for (int idx = tid; idx < NMID * 4 * 64 * 8 / 2; idx += 256)
        ((u32*)sWf)[idx] = 0u;
    for (int idx = tid; idx < 32; idx += 256) {
        int h2 = idx >> 4, reg = idx & 15;
        int n = (reg & 3) + 8 * (reg >> 2) + 4 * h2;
        float w0 = 0.f, w1 = 0.f, b = 0.f, wo = 0.f;
        if (n < HID) { w0 = W_in[n * 2]; w1 = W_in[n * 2 + 1]; b = b_in[n]; wo = W_out[n]; }
        sIn[idx * 4 + 0] = w0; sIn[idx * 4 + 1] = w1;
        sIn[idx * 4 + 2] = b;  sIn[idx * 4 + 3] = wo;
    }
    __syncthreads();
    for (int idx = tid; idx < NMID * HID * (HID + 1); idx += 256) {
        int layer = idx / (HID * (HID + 1));
        int rem   = idx % (HID * (HID + 1));
        int j = rem / (HID + 1);
        int k = rem % (HID + 1);
        float w = (k < HID) ? W_mid[(layer * HID + j) * HID + k] : b_mid[layer * HID + j];
        u32 whib = bf16_bits(w);
        u32 wlob = bf16_bits(w - __builtin_bit_cast(float, whib << 16));
        int s = k >> 4, kk = k & 15, h2 = kk >> 3, r = kk & 7;
        int lane = j + 32 * h2;
        sWf[(((layer * 4) + s) * 64 + lane) * 8 + r]     = (short)whib;   // hi part
        sWf[(((layer * 4) + 2 + s) * 64 + lane) * 8 + r] = (short)wlob;   // lo part
    }
    __syncthreads();

    const int lane = tid & 63;
    const int wv   = tid >> 6;
    const int p    = lane & 31;
    const int hi   = lane >> 5;
    const int P    = blockIdx.x * 128 + wv * 32 + p;

    const float2 xv = reinterpret_cast<const float2*>(x)[P];
    const float x0 = xv.x, x1 = xv.y;
    const float bo = b_out[0];

    const float4* sIn4 = reinterpret_cast<const float4*>(sIn);

    float vh[12], vs[12], vt[12], vx[12], vxx[12];

    // ---- input layer (fp32, exact) ----
    #pragma unroll
    for (int r = 0; r < 12; ++r) {
        float4 t = sIn4[hi * 16 + r];
        float z = fmaf(t.x, x0, fmaf(t.y, x1, t.z));
        float e = __expf(2.0f * z);
        float a = 1.0f - __fdividef(2.0f, e + 1.0f);
        float s = fmaf(-a, a, 1.0f);
        float sx = s * t.y;
        vh[r] = a; vt[r] = s * t.x; vx[r] = sx;
        vxx[r] = -2.0f * a * sx * t.y;
    }

    const f32x16 zz = 0.0f;
    const short8* afp = reinterpret_cast<const short8*>(sWf);

    for (int layer = 0; layer < NMID; ++layer) {
        const short8 wh0 = afp[(layer * 4 + 0) * 64 + lane];
        const short8 wh1 = afp[(layer * 4 + 1) * 64 + lane];
        const short8 wl0 = afp[(layer * 4 + 2) * 64 + lane];
        const short8 wl1 = afp[(layer * 4 + 3) * 64 + lane];

        // ---- group 1: H and T streams ----
        {
            u32 dh[8], dhl[8], dt[8], dtl[8];
            build_frags(vh, hi, 0x00003F80u, dh, dhl);   // bias col: hi=1.0, lo=0.0
            build_frags(vt, hi, 0u, dt, dtl);

            f32x16 aH = MF(wh0, dh, 0, zz);  f32x16 aT = MF(wh0, dt, 0, zz);
            aH = MF(wh1, dh, 4, aH);         aT = MF(wh1, dt, 4, aT);
            aH = MF(wh0, dhl, 0, aH);        aT = MF(wh0, dtl, 0, aT);
            aH = MF(wh1, dhl, 4, aH);        aT = MF(wh1, dtl, 4, aT);
            aH = MF(wl0, dh, 0, aH);         aT = MF(wl0, dt, 0, aT);
            aH = MF(wl1, dh, 4, aH);         aT = MF(wl1, dt, 4, aT);

            #pragma unroll
            for (int r = 0; r < 12; ++r) {
                float z = aH[r];
                float e = __expf(2.0f * z);
                float a = 1.0f - __fdividef(2.0f, e + 1.0f);
                float s = fmaf(-a, a, 1.0f);
                vh[r] = a; vs[r] = s; vt[r] = s * aT[r];
            }
        }

        // ---- group 2: X and Q streams ----
        {
            u32 dx[8], dxl[8], dq[8], dql[8];
            build_frags(vx, hi, 0u, dx, dxl);
            build_frags(vxx, hi, 0u, dq, dql);

            f32x16 aX = MF(wh0, dx, 0, zz);  f32x16 aQ = MF(wh0, dq, 0, zz);
            aX = MF(wh1, dx, 4, aX);         aQ = MF(wh1, dq, 4, aQ);
            aX = MF(wh0, dxl, 0, aX);        aQ = MF(wh0, dql, 0, aQ);
            aX = MF(wh1, dxl, 4, aX);        aQ = MF(wh1, dql, 4, aQ);
            aX = MF(wl0, dx, 0, aX);         aQ = MF(wl0, dq, 0, aQ);
            aX = MF(wl1, dx, 4, aX);         aQ = MF(wl1, dq, 4, aQ);

            #pragma unroll
            for (int r = 0; r < 12; ++r) {
                float zx = aX[r];
                float a = vh[r], s = vs[r];
                float nx = s * zx;
                float t2 = 2.0f * a * nx;
                vx[r] = nx;
                vxx[r] = fmaf(-t2, zx, s * aQ[r]);
            }
        }
    }

    // ---- output layer ----
    float f = 0.f, ft = 0.f, fx = 0.f, fxx = 0.f;
    #pragma unroll
    for (int r = 0; r < 12; ++r) {
        float4 t = sIn4[hi * 16 + r];
        f   = fmaf(t.w, vh[r],  f);
        ft  = fmaf(t.w, vt[r],  ft);
        fx  = fmaf(t.w, vx[r],  fx);
        fxx = fmaf(t.w, vxx[r], fxx);
    }
    f   += __shfl_xor(f, 32);
    ft  += __shfl_xor(ft, 32);
    fx  += __shfl_xor(fx, 32);
    fxx += __shfl_xor(fxx, 32);
    f += bo;

    if (!hi) {
        const float pde = 0.5f * x1 * x1 + ft + 0.5f * fxx + 0.5f * x1 * fx
                          - 0.069444444444444f * fx * fx;
        out[P] = f;
        out[NPTS + P] = pde;
    }
}

extern "C" void kernel_launch(void* const* d_in, const int* in_sizes, int n_in,
                              void* d_out, int out_size, void* d_ws, size_t ws_size,
                              hipStream_t stream) {
    const float* x     = (const float*)d_in[0];
    const float* W_in  = (const float*)d_in[1];
    const float* b_in  = (const float*)d_in[2];
    const float* W_mid = (const float*)d_in[3];
    const float* b_mid = (const float*)d_in[4];
    const float* W_out = (const float*)d_in[5];
    const float* b_out = (const float*)d_in[6];
    float* out = (float*)d_out;

    hipLaunchKernelGGL(pde_mfma_kernel, dim3(NPTS / 128), dim3(256), 0, stream,
                       x, W_in, b_in, W_mid, b_mid, W_out, b_out, out);
}

// Round 7
// 85.777 us; speedup vs baseline: 1.0257x; 1.0257x over previous
//
#include <hip/hip_runtime.h>
#include <hip/hip_bf16.h>

#define NPTS 262144
#define HID  20
#define NMID 8

typedef float f32x16 __attribute__((ext_vector_type(16)));
typedef short short8 __attribute__((ext_vector_type(8)));
typedef unsigned int u32;

__device__ __forceinline__ u32 bf16_bits(float f) {
    u32 u = __builtin_bit_cast(u32, f);
    return (u + 0x7FFFu + ((u >> 16) & 1u)) >> 16;   // RNE (staging use)
}

// packed bf16 pair via the library converter (tripwire-green in R6)
__device__ __forceinline__ u32 pkrn(float a, float b) {
    __hip_bfloat162 t = __float22bfloat162_rn(make_float2(a, b));  // x=lo, y=hi
    u32 r; __builtin_memcpy(&r, &t, 4); return r;
}

__device__ __forceinline__ float flo(u32 c) { return __builtin_bit_cast(float, c << 16); }
__device__ __forceinline__ float fhi(u32 c) { return __builtin_bit_cast(float, c & 0xFFFF0000u); }

__device__ __forceinline__ short8 mk_frag(const u32* d, int o) {
    uint4 v = make_uint4(d[o + 0], d[o + 1], d[o + 2], d[o + 3]);
    return __builtin_bit_cast(short8, v);
}

// Weight k-columns are PERMUTED at staging (k -> k^12 for k in [4,12)) so that
// the B-fragment needed by the next MFMA equals the LOCAL C/D register order:
// both lane halves build [pk(v0,v1),pk(v2,v3),pk(v4,v5),pk(v6,v7),
//                         pk(v8,v9),pk(v10,v11), bias, 0] — no cross-lane ops.
// (hi-lane s=1 slots are k=24..31 where A columns are zero -> don't-care.)
__device__ __forceinline__ void build_frags(const float* v, u32 bias,
                                            u32* bh, u32* bl) {
    u32 h01 = pkrn(v[0], v[1]),   h23 = pkrn(v[2], v[3]);
    u32 h45 = pkrn(v[4], v[5]),   h67 = pkrn(v[6], v[7]);
    u32 h89 = pkrn(v[8], v[9]),   hAB = pkrn(v[10], v[11]);
    bh[0] = h01; bh[1] = h23; bh[2] = h45; bh[3] = h67;
    bh[4] = h89; bh[5] = hAB; bh[6] = bias; bh[7] = 0u;
    bl[0] = pkrn(v[0] - flo(h01), v[1] - fhi(h01));
    bl[1] = pkrn(v[2] - flo(h23), v[3] - fhi(h23));
    bl[2] = pkrn(v[4] - flo(h45), v[5] - fhi(h45));
    bl[3] = pkrn(v[6] - flo(h67), v[7] - fhi(h67));
    bl[4] = pkrn(v[8] - flo(h89), v[9] - fhi(h89));
    bl[5] = pkrn(v[10] - flo(hAB), v[11] - fhi(hAB));
    bl[6] = 0u; bl[7] = 0u;
}

#define MF(A, D, O, C) __builtin_amdgcn_mfma_f32_32x32x16_bf16(A, mk_frag(D, O), C, 0, 0, 0)

__launch_bounds__(256, 4)
__global__ void pde_mfma_kernel(const float* __restrict__ x,
                                const float* __restrict__ W_in,
                                const float* __restrict__ b_in,
                                const float* __restrict__ W_mid,
                                const float* __restrict__ b_mid,
                                const float* __restrict__ W_out,
                                const float* __restrict__ b_out,
                                float* __restrict__ out) {
    // A-frags: [layer][part: hi s=0, hi s=1, lo s=0, lo s=1][lane][8]; bias as col 20.
    __shared__ short sWf[NMID * 4 * 64 * 8];   // 32 KB
    __shared__ float sIn[2 * 16 * 4];

    const int tid = threadIdx.x;

    for (int idx = tid; idx < NMID * 4 * 64 * 8 / 2; idx += 256)
        ((u32*)sWf)[idx] = 0u;
    for (int idx = tid; idx < 32; idx += 256) {
        int h2 = idx >> 4, reg = idx & 15;
        int n = (reg & 3) + 8 * (reg >> 2) + 4 * h2;
        float w0 = 0.f, w1 = 0.f, b = 0.f, wo = 0.f;
        if (n < HID) { w0 = W_in[n * 2]; w1 = W_in[n * 2 + 1]; b = b_in[n]; wo = W_out[n]; }
        sIn[idx * 4 + 0] = w0; sIn[idx * 4 + 1] = w1;
        sIn[idx * 4 + 2] = b;  sIn[idx * 4 + 3] = wo;
    }
    __syncthreads();
    for (int idx = tid; idx < NMID * HID * (HID + 1); idx += 256) {
        int layer = idx / (HID * (HID + 1));
        int rem   = idx % (HID * (HID + 1));
        int j = rem / (HID + 1);
        int k = rem % (HID + 1);
        float w = (k < HID) ? W_mid[(layer * HID + j) * HID + k] : b_mid[layer * HID + j];
        u32 whib = bf16_bits(w);
        u32 wlob = bf16_bits(w - __builtin_bit_cast(float, whib << 16));
        int kp = (k >= 4 && k < 12) ? (k ^ 12) : k;   // column permutation
        int s = kp >> 4, kk = kp & 15, h2 = kk >> 3, r = kk & 7;
        int lane = j + 32 * h2;
        sWf[(((layer * 4) + s) * 64 + lane) * 8 + r]     = (short)whib;   // hi part
        sWf[(((layer * 4) + 2 + s) * 64 + lane) * 8 + r] = (short)wlob;   // lo part
    }
    __syncthreads();

    const int lane = tid & 63;
    const int wv   = tid >> 6;
    const int p    = lane & 31;
    const int hi   = lane >> 5;
    const int P    = blockIdx.x * 128 + wv * 32 + p;

    const float2 xv = reinterpret_cast<const float2*>(x)[P];
    const float x0 = xv.x, x1 = xv.y;
    const float bo = b_out[0];

    const float4* sIn4 = reinterpret_cast<const float4*>(sIn);

    float vh[12], vs[12], vt[12], vx[12], vxx[12];

    // ---- input layer (fp32, exact) ----
    #pragma unroll
    for (int r = 0; r < 12; ++r) {
        float4 t = sIn4[hi * 16 + r];
        float z = fmaf(t.x, x0, fmaf(t.y, x1, t.z));
        float e = __expf(2.0f * z);
        float a = 1.0f - __fdividef(2.0f, e + 1.0f);
        float s = fmaf(-a, a, 1.0f);
        float sx = s * t.y;
        vh[r] = a; vt[r] = s * t.x; vx[r] = sx;
        vxx[r] = -2.0f * a * sx * t.y;
    }

    const f32x16 zz = 0.0f;
    const short8* afp = reinterpret_cast<const short8*>(sWf);

    for (int layer = 0; layer < NMID; ++layer) {
        const short8 wh0 = afp[(layer * 4 + 0) * 64 + lane];
        const short8 wh1 = afp[(layer * 4 + 1) * 64 + lane];
        const short8 wl0 = afp[(layer * 4 + 2) * 64 + lane];
        const short8 wl1 = afp[(layer * 4 + 3) * 64 + lane];

        // ---- group 1: H and T streams ----
        {
            u32 dh[8], dhl[8], dt[8], dtl[8];
            build_frags(vh, 0x00003F80u, dh, dhl);   // bias col: hi=1.0, lo=0.0
            build_frags(vt, 0u, dt, dtl);

            f32x16 aH = MF(wh0, dh, 0, zz);  f32x16 aT = MF(wh0, dt, 0, zz);
            aH = MF(wh1, dh, 4, aH);         aT = MF(wh1, dt, 4, aT);
            aH = MF(wh0, dhl, 0, aH);        aT = MF(wh0, dtl, 0, aT);
            aH = MF(wh1, dhl, 4, aH);        aT = MF(wh1, dtl, 4, aT);
            aH = MF(wl0, dh, 0, aH);         aT = MF(wl0, dt, 0, aT);
            aH = MF(wl1, dh, 4, aH);         aT = MF(wl1, dt, 4, aT);

            #pragma unroll
            for (int r = 0; r < 12; ++r) {
                float z = aH[r];
                float e = __expf(2.0f * z);
                float a = 1.0f - __fdividef(2.0f, e + 1.0f);
                float s = fmaf(-a, a, 1.0f);
                vh[r] = a; vs[r] = s; vt[r] = s * aT[r];
            }
        }

        // ---- group 2: X and Q streams ----
        {
            u32 dx[8], dxl[8], dq[8], dql[8];
            build_frags(vx, 0u, dx, dxl);
            build_frags(vxx, 0u, dq, dql);

            f32x16 aX = MF(wh0, dx, 0, zz);  f32x16 aQ = MF(wh0, dq, 0, zz);
            aX = MF(wh1, dx, 4, aX);         aQ = MF(wh1, dq, 4, aQ);
            aX = MF(wh0, dxl, 0, aX);        aQ = MF(wh0, dql, 0, aQ);
            aX = MF(wh1, dxl, 4, aX);        aQ = MF(wh1, dql, 4, aQ);
            aX = MF(wl0, dx, 0, aX);         aQ = MF(wl0, dq, 0, aQ);
            aX = MF(wl1, dx, 4, aX);         aQ = MF(wl1, dq, 4, aQ);

            #pragma unroll
            for (int r = 0; r < 12; ++r) {
                float zx = aX[r];
                float a = vh[r], s = vs[r];
                float nx = s * zx;
                float t2 = 2.0f * a * nx;
                vx[r] = nx;
                vxx[r] = fmaf(-t2, zx, s * aQ[r]);
            }
        }
    }

    // ---- output layer ----
    float f = 0.f, ft = 0.f, fx = 0.f, fxx = 0.f;
    #pragma unroll
    for (int r = 0; r < 12; ++r) {
        float4 t = sIn4[hi * 16 + r];
        f   = fmaf(t.w, vh[r],  f);
        ft  = fmaf(t.w, vt[r],  ft);
        fx  = fmaf(t.w, vx[r],  fx);
        fxx = fmaf(t.w, vxx[r], fxx);
    }
    f   += __shfl_xor(f, 32);
    ft  += __shfl_xor(ft, 32);
    fx  += __shfl_xor(fx, 32);
    fxx += __shfl_xor(fxx, 32);
    f += bo;

    if (!hi) {
        const float pde = 0.5f * x1 * x1 + ft + 0.5f * fxx + 0.5f * x1 * fx
                          - 0.069444444444444f * fx * fx;
        out[P] = f;
        out[NPTS + P] = pde;
    }
}

extern "C" void kernel_launch(void* const* d_in, const int* in_sizes, int n_in,
                              void* d_out, int out_size, void* d_ws, size_t ws_size,
                              hipStream_t stream) {
    const float* x     = (const float*)d_in[0];
    const float* W_in  = (const float*)d_in[1];
    const float* b_in  = (const float*)d_in[2];
    const float* W_mid = (const float*)d_in[3];
    const float* b_mid = (const float*)d_in[4];
    const float* W_out = (const float*)d_in[5];
    const float* b_out = (const float*)d_in[6];
    float* out = (float*)d_out;

    hipLaunchKernelGGL(pde_mfma_kernel, dim3(NPTS / 128), dim3(256), 0, stream,
                       x, W_in, b_in, W_mid, b_mid, W_out, b_out, out);
}

// Round 8
// 81.521 us; speedup vs baseline: 1.0793x; 1.0522x over previous
//
#include <hip/hip_runtime.h>

#define NPTS 262144
#define HID  20
#define NMID 8

typedef float f32x16 __attribute__((ext_vector_type(16)));
typedef short short8 __attribute__((ext_vector_type(8)));
typedef unsigned int u32;

__device__ __forceinline__ u32 bf16_bits(float f) {
    u32 u = __builtin_bit_cast(u32, f);
    return (u + 0x7FFFu + ((u >> 16) & 1u)) >> 16;   // RNE (weight staging only)
}

// Round-half-up bf16 pair pack: 2 adds + 1 byte-perm. Result = bf16(a) | bf16(b)<<16.
// Half-up == RNE except on exact ties (same 1/2-ulp bound); values are finite/bounded.
__device__ __forceinline__ u32 pk2(float a, float b) {
    u32 ua = __builtin_bit_cast(u32, a) + 0x8000u;
    u32 ub = __builtin_bit_cast(u32, b) + 0x8000u;
    return __builtin_amdgcn_perm(ub, ua, 0x07060302u);  // bytes: ua[2],ua[3],ub[2],ub[3]
}

__device__ __forceinline__ float flo(u32 c) { return __builtin_bit_cast(float, c << 16); }
__device__ __forceinline__ float fhi(u32 c) { return __builtin_bit_cast(float, c & 0xFFFF0000u); }

__device__ __forceinline__ short8 mk_frag(const u32* d, int o) {
    uint4 v = make_uint4(d[o + 0], d[o + 1], d[o + 2], d[o + 3]);
    return __builtin_bit_cast(short8, v);
}

// Weight k-columns PERMUTED at staging (k -> k^12 for k in [4,12)) so the needed
// B-fragment equals the LOCAL C/D register order for both lane halves — no
// cross-lane ops. (hi-lane s=1 slots are k=24..31 where A columns are zero.)
__device__ __forceinline__ void build_frags(const float* v, u32 bias,
                                            u32* bh, u32* bl) {
    u32 h01 = pk2(v[0], v[1]),   h23 = pk2(v[2], v[3]);
    u32 h45 = pk2(v[4], v[5]),   h67 = pk2(v[6], v[7]);
    u32 h89 = pk2(v[8], v[9]),   hAB = pk2(v[10], v[11]);
    bh[0] = h01; bh[1] = h23; bh[2] = h45; bh[3] = h67;
    bh[4] = h89; bh[5] = hAB; bh[6] = bias; bh[7] = 0u;
    bl[0] = pk2(v[0] - flo(h01), v[1] - fhi(h01));
    bl[1] = pk2(v[2] - flo(h23), v[3] - fhi(h23));
    bl[2] = pk2(v[4] - flo(h45), v[5] - fhi(h45));
    bl[3] = pk2(v[6] - flo(h67), v[7] - fhi(h67));
    bl[4] = pk2(v[8] - flo(h89), v[9] - fhi(h89));
    bl[5] = pk2(v[10] - flo(hAB), v[11] - fhi(hAB));
    bl[6] = 0u; bl[7] = 0u;
}

#define MF(A, D, O, C) __builtin_amdgcn_mfma_f32_32x32x16_bf16(A, mk_frag(D, O), C, 0, 0, 0)

__launch_bounds__(256, 4)
__global__ void pde_mfma_kernel(const float* __restrict__ x,
                                const float* __restrict__ W_in,
                                const float* __restrict__ b_in,
                                const float* __restrict__ W_mid,
                                const float* __restrict__ b_mid,
                                const float* __restrict__ W_out,
                                const float* __restrict__ b_out,
                                float* __restrict__ out) {
    // A-frags: [layer][part: hi s=0, hi s=1, lo s=0, lo s=1][lane][8]; bias as col 20.
    __shared__ short sWf[NMID * 4 * 64 * 8];   // 32 KB
    __shared__ float sIn[2 * 16 * 4];

    const int tid = threadIdx.x;

    for (int idx = tid; idx < NMID * 4 * 64 * 8 / 2; idx += 256)
        ((u32*)sWf)[idx] = 0u;
    for (int idx = tid; idx < 32; idx += 256) {
        int h2 = idx >> 4, reg = idx & 15;
        int n = (reg & 3) + 8 * (reg >> 2) + 4 * h2;
        float w0 = 0.f, w1 = 0.f, b = 0.f, wo = 0.f;
        if (n < HID) { w0 = W_in[n * 2]; w1 = W_in[n * 2 + 1]; b = b_in[n]; wo = W_out[n]; }
        sIn[idx * 4 + 0] = w0; sIn[idx * 4 + 1] = w1;
        sIn[idx * 4 + 2] = b;  sIn[idx * 4 + 3] = wo;
    }
    __syncthreads();
    for (int idx = tid; idx < NMID * HID * (HID + 1); idx += 256) {
        int layer = idx / (HID * (HID + 1));
        int rem   = idx % (HID * (HID + 1));
        int j = rem / (HID + 1);
        int k = rem % (HID + 1);
        float w = (k < HID) ? W_mid[(layer * HID + j) * HID + k] : b_mid[layer * HID + j];
        u32 whib = bf16_bits(w);
        u32 wlob = bf16_bits(w - __builtin_bit_cast(float, whib << 16));
        int kp = (k >= 4 && k < 12) ? (k ^ 12) : k;   // column permutation
        int s = kp >> 4, kk = kp & 15, h2 = kk >> 3, r = kk & 7;
        int lane = j + 32 * h2;
        sWf[(((layer * 4) + s) * 64 + lane) * 8 + r]     = (short)whib;   // hi part
        sWf[(((layer * 4) + 2 + s) * 64 + lane) * 8 + r] = (short)wlob;   // lo part
    }
    __syncthreads();

    const int lane = tid & 63;
    const int wv   = tid >> 6;
    const int p    = lane & 31;
    const int hi   = lane >> 5;
    const int P    = blockIdx.x * 128 + wv * 32 + p;

    const float2 xv = reinterpret_cast<const float2*>(x)[P];
    const float x0 = xv.x, x1 = xv.y;
    const float bo = b_out[0];

    const float4* sIn4 = reinterpret_cast<const float4*>(sIn);

    float vh[12], vs[12], vt[12], vx[12], vxx[12];

    // ---- input layer (fp32, exact) ----
    #pragma unroll
    for (int r = 0; r < 12; ++r) {
        float4 t = sIn4[hi * 16 + r];
        float z = fmaf(t.x, x0, fmaf(t.y, x1, t.z));
        float e = __expf(2.0f * z);
        float a = 1.0f - __fdividef(2.0f, e + 1.0f);
        float s = fmaf(-a, a, 1.0f);
        float sx = s * t.y;
        vh[r] = a; vt[r] = s * t.x; vx[r] = sx;
        vxx[r] = -2.0f * a * sx * t.y;
    }

    const f32x16 zz = 0.0f;
    const short8* afp = reinterpret_cast<const short8*>(sWf);

    for (int layer = 0; layer < NMID; ++layer) {
        const short8 wh0 = afp[(layer * 4 + 0) * 64 + lane];
        const short8 wh1 = afp[(layer * 4 + 1) * 64 + lane];
        const short8 wl0 = afp[(layer * 4 + 2) * 64 + lane];
        const short8 wl1 = afp[(layer * 4 + 3) * 64 + lane];

        // ---- group 1: H and T streams ----
        {
            u32 dh[8], dhl[8], dt[8], dtl[8];
            build_frags(vh, 0x00003F80u, dh, dhl);   // bias col: hi=1.0, lo=0.0
            build_frags(vt, 0u, dt, dtl);

            f32x16 aH = MF(wh0, dh, 0, zz);  f32x16 aT = MF(wh0, dt, 0, zz);
            aH = MF(wh1, dh, 4, aH);         aT = MF(wh1, dt, 4, aT);
            aH = MF(wh0, dhl, 0, aH);        aT = MF(wh0, dtl, 0, aT);
            aH = MF(wh1, dhl, 4, aH);        aT = MF(wh1, dtl, 4, aT);
            aH = MF(wl0, dh, 0, aH);         aT = MF(wl0, dt, 0, aT);
            aH = MF(wl1, dh, 4, aH);         aT = MF(wl1, dt, 4, aT);

            #pragma unroll
            for (int r = 0; r < 12; ++r) {
                float z = aH[r];
                float e = __expf(2.0f * z);
                float a = 1.0f - __fdividef(2.0f, e + 1.0f);
                float s = fmaf(-a, a, 1.0f);
                vh[r] = a; vs[r] = s; vt[r] = s * aT[r];
            }
        }

        // ---- group 2: X and Q streams ----
        {
            u32 dx[8], dxl[8], dq[8], dql[8];
            build_frags(vx, 0u, dx, dxl);
            build_frags(vxx, 0u, dq, dql);

            f32x16 aX = MF(wh0, dx, 0, zz);  f32x16 aQ = MF(wh0, dq, 0, zz);
            aX = MF(wh1, dx, 4, aX);         aQ = MF(wh1, dq, 4, aQ);
            aX = MF(wh0, dxl, 0, aX);        aQ = MF(wh0, dql, 0, aQ);
            aX = MF(wh1, dxl, 4, aX);        aQ = MF(wh1, dql, 4, aQ);
            aX = MF(wl0, dx, 0, aX);         aQ = MF(wl0, dq, 0, aQ);
            aX = MF(wl1, dx, 4, aX);         aQ = MF(wl1, dq, 4, aQ);

            #pragma unroll
            for (int r = 0; r < 12; ++r) {
                float zx = aX[r];
                float a = vh[r], s = vs[r];
                float nx = s * zx;
                float t2 = 2.0f * a * nx;
                vx[r] = nx;
                vxx[r] = fmaf(-t2, zx, s * aQ[r]);
            }
        }
    }

    // ---- output layer ----
    float f = 0.f, ft = 0.f, fx = 0.f, fxx = 0.f;
    #pragma unroll
    for (int r = 0; r < 12; ++r) {
        float4 t = sIn4[hi * 16 + r];
        f   = fmaf(t.w, vh[r],  f);
        ft  = fmaf(t.w, vt[r],  ft);
        fx  = fmaf(t.w, vx[r],  fx);
        fxx = fmaf(t.w, vxx[r], fxx);
    }
    f   += __shfl_xor(f, 32);
    ft  += __shfl_xor(ft, 32);
    fx  += __shfl_xor(fx, 32);
    fxx += __shfl_xor(fxx, 32);
    f += bo;

    if (!hi) {
        const float pde = 0.5f * x1 * x1 + ft + 0.5f * fxx + 0.5f * x1 * fx
                          - 0.069444444444444f * fx * fx;
        out[P] = f;
        out[NPTS + P] = pde;
    }
}

extern "C" void kernel_launch(void* const* d_in, const int* in_sizes, int n_in,
                              void* d_out, int out_size, void* d_ws, size_t ws_size,
                              hipStream_t stream) {
    const float* x     = (const float*)d_in[0];
    const float* W_in  = (const float*)d_in[1];
    const float* b_in  = (const float*)d_in[2];
    const float* W_mid = (const float*)d_in[3];
    const float* b_mid = (const float*)d_in[4];
    const float* W_out = (const float*)d_in[5];
    const float* b_out = (const float*)d_in[6];
    float* out = (float*)d_out;

    hipLaunchKernelGGL(pde_mfma_kernel, dim3(NPTS / 128), dim3(256), 0, stream,
                       x, W_in, b_in, W_mid, b_mid, W_out, b_out, out);
}

// Round 10
// 63.752 us; speedup vs baseline: 1.3801x; 1.2787x over previous
//
#include <hip/hip_runtime.h>

#define NPTS 262144
#define HID  20
#define NMID 8

typedef float f32x16 __attribute__((ext_vector_type(16)));
typedef short short8 __attribute__((ext_vector_type(8)));
typedef unsigned int u32;

__device__ __forceinline__ u32 bf16_bits(float f) {
    u32 u = __builtin_bit_cast(u32, f);
    return (u + 0x7FFFu + ((u >> 16) & 1u)) >> 16;   // RNE (weight staging only)
}

// Round-half-up bf16 pair pack: 2 adds + 1 byte-perm. Result = bf16(a) | bf16(b)<<16.
__device__ __forceinline__ u32 pk2(float a, float b) {
    u32 ua = __builtin_bit_cast(u32, a) + 0x8000u;
    u32 ub = __builtin_bit_cast(u32, b) + 0x8000u;
    return __builtin_amdgcn_perm(ub, ua, 0x07060302u);  // bytes: ua[2],ua[3],ub[2],ub[3]
}

__device__ __forceinline__ float flo(u32 c) { return __builtin_bit_cast(float, c << 16); }
__device__ __forceinline__ float fhi(u32 c) { return __builtin_bit_cast(float, c & 0xFFFF0000u); }

__device__ __forceinline__ short8 mk_frag(const u32* d, int o) {
    uint4 v = make_uint4(d[o + 0], d[o + 1], d[o + 2], d[o + 3]);
    return __builtin_bit_cast(short8, v);
}

// Weight k-columns PERMUTED at staging (k -> k^12 for k in [4,12)) so the needed
// B-fragment equals the LOCAL C/D register order for both lane halves — no
// cross-lane ops. (hi-lane s=1 slots are k=24..31 where A columns are zero.)
// H stream: hi + lo-residual fragments (full 3-term expansion).
__device__ __forceinline__ void build_frags_hl(const float* v, u32 bias,
                                               u32* bh, u32* bl) {
    u32 h01 = pk2(v[0], v[1]),   h23 = pk2(v[2], v[3]);
    u32 h45 = pk2(v[4], v[5]),   h67 = pk2(v[6], v[7]);
    u32 h89 = pk2(v[8], v[9]),   hAB = pk2(v[10], v[11]);
    bh[0] = h01; bh[1] = h23; bh[2] = h45; bh[3] = h67;
    bh[4] = h89; bh[5] = hAB; bh[6] = bias; bh[7] = 0u;
    bl[0] = pk2(v[0] - flo(h01), v[1] - fhi(h01));
    bl[1] = pk2(v[2] - flo(h23), v[3] - fhi(h23));
    bl[2] = pk2(v[4] - flo(h45), v[5] - fhi(h45));
    bl[3] = pk2(v[6] - flo(h67), v[7] - fhi(h67));
    bl[4] = pk2(v[8] - flo(h89), v[9] - fhi(h89));
    bl[5] = pk2(v[10] - flo(hAB), v[11] - fhi(hAB));
    bl[6] = 0u; bl[7] = 0u;
}

// Derivative streams (T/X/Q): single-bf16 activation fragment; weights remain
// hi/lo-exact, so per-layer relative error ~2^-9 on derivative streams only.
__device__ __forceinline__ void build_frags_s(const float* v, u32* bh) {
    bh[0] = pk2(v[0], v[1]);   bh[1] = pk2(v[2], v[3]);
    bh[2] = pk2(v[4], v[5]);   bh[3] = pk2(v[6], v[7]);
    bh[4] = pk2(v[8], v[9]);   bh[5] = pk2(v[10], v[11]);
    bh[6] = 0u; bh[7] = 0u;
}

#define MF(A, D, O, C) __builtin_amdgcn_mfma_f32_32x32x16_bf16(A, mk_frag(D, O), C, 0, 0, 0)

__launch_bounds__(256, 4)
__global__ void pde_mfma_kernel(const float* __restrict__ x,
                                const float* __restrict__ W_in,
                                const float* __restrict__ b_in,
                                const float* __restrict__ W_mid,
                                const float* __restrict__ b_mid,
                                const float* __restrict__ W_out,
                                const float* __restrict__ b_out,
                                float* __restrict__ out) {
    // A-frags: [layer][part: hi s=0, hi s=1, lo s=0, lo s=1][lane][8]; bias as col 20.
    __shared__ short sWf[NMID * 4 * 64 * 8];   // 32 KB
    __shared__ float sIn[2 * 16 * 4];

    const int tid = threadIdx.x;

    for (int idx = tid; idx < NMID * 4 * 64 * 8 / 2; idx += 256)
        ((u32*)sWf)[idx] = 0u;
    for (int idx = tid; idx < 32; idx += 256) {
        int h2 = idx >> 4, reg = idx & 15;
        int n = (reg & 3) + 8 * (reg >> 2) + 4 * h2;
        float w0 = 0.f, w1 = 0.f, b = 0.f, wo = 0.f;
        if (n < HID) { w0 = W_in[n * 2]; w1 = W_in[n * 2 + 1]; b = b_in[n]; wo = W_out[n]; }
        sIn[idx * 4 + 0] = w0; sIn[idx * 4 + 1] = w1;
        sIn[idx * 4 + 2] = b;  sIn[idx * 4 + 3] = wo;
    }
    __syncthreads();
    for (int idx = tid; idx < NMID * HID * (HID + 1); idx += 256) {
        int layer = idx / (HID * (HID + 1));
        int rem   = idx % (HID * (HID + 1));
        int j = rem / (HID + 1);
        int k = rem % (HID + 1);
        float w = (k < HID) ? W_mid[(layer * HID + j) * HID + k] : b_mid[layer * HID + j];
        u32 whib = bf16_bits(w);
        u32 wlob = bf16_bits(w - __builtin_bit_cast(float, whib << 16));
        int kp = (k >= 4 && k < 12) ? (k ^ 12) : k;   // column permutation
        int s = kp >> 4, kk = kp & 15, h2 = kk >> 3, r = kk & 7;
        int lane = j + 32 * h2;
        sWf[(((layer * 4) + s) * 64 + lane) * 8 + r]     = (short)whib;   // hi part
        sWf[(((layer * 4) + 2 + s) * 64 + lane) * 8 + r] = (short)wlob;   // lo part
    }
    __syncthreads();

    const int lane = tid & 63;
    const int wv   = tid >> 6;
    const int p    = lane & 31;
    const int hi   = lane >> 5;
    const int P    = blockIdx.x * 128 + wv * 32 + p;

    const float2 xv = reinterpret_cast<const float2*>(x)[P];
    const float x0 = xv.x, x1 = xv.y;
    const float bo = b_out[0];

    const float4* sIn4 = reinterpret_cast<const float4*>(sIn);

    float vh[12], vs[12], vt[12], vx[12], vxx[12];

    // ---- input layer (fp32, exact) ----
    #pragma unroll
    for (int r = 0; r < 12; ++r) {
        float4 t = sIn4[hi * 16 + r];
        float z = fmaf(t.x, x0, fmaf(t.y, x1, t.z));
        float e = __expf(2.0f * z);
        float a = 1.0f - __fdividef(2.0f, e + 1.0f);
        float s = fmaf(-a, a, 1.0f);
        float sx = s * t.y;
        vh[r] = a; vt[r] = s * t.x; vx[r] = sx;
        vxx[r] = -2.0f * a * sx * t.y;
    }

    const f32x16 zz = 0.0f;
    const short8* afp = reinterpret_cast<const short8*>(sWf);

    for (int layer = 0; layer < NMID; ++layer) {
        const short8 wh0 = afp[(layer * 4 + 0) * 64 + lane];
        const short8 wh1 = afp[(layer * 4 + 1) * 64 + lane];
        const short8 wl0 = afp[(layer * 4 + 2) * 64 + lane];
        const short8 wl1 = afp[(layer * 4 + 3) * 64 + lane];

        // ---- group 1: H (hi+lo 3-term) and T (single) ----
        {
            u32 dh[8], dhl[8], dt[8];
            build_frags_hl(vh, 0x00003F80u, dh, dhl);   // bias col: hi=1.0, lo=0.0
            build_frags_s(vt, dt);

            f32x16 aH = MF(wh0, dh, 0, zz);  f32x16 aT = MF(wh0, dt, 0, zz);
            aH = MF(wh1, dh, 4, aH);         aT = MF(wh1, dt, 4, aT);
            aH = MF(wh0, dhl, 0, aH);        aT = MF(wl0, dt, 0, aT);
            aH = MF(wh1, dhl, 4, aH);        aT = MF(wl1, dt, 4, aT);
            aH = MF(wl0, dh, 0, aH);
            aH = MF(wl1, dh, 4, aH);

            #pragma unroll
            for (int r = 0; r < 12; ++r) {
                float z = aH[r];
                float e = __expf(2.0f * z);
                float a = 1.0f - __fdividef(2.0f, e + 1.0f);
                float s = fmaf(-a, a, 1.0f);
                vh[r] = a; vs[r] = s; vt[r] = s * aT[r];
            }
        }

        // ---- group 2: X and Q streams (single) ----
        {
            u32 dx[8], dq[8];
            build_frags_s(vx, dx);
            build_frags_s(vxx, dq);

            f32x16 aX = MF(wh0, dx, 0, zz);  f32x16 aQ = MF(wh0, dq, 0, zz);
            aX = MF(wh1, dx, 4, aX);         aQ = MF(wh1, dq, 4, aQ);
            aX = MF(wl0, dx, 0, aX);         aQ = MF(wl0, dq, 0, aQ);
            aX = MF(wl1, dx, 4, aX);         aQ = MF(wl1, dq, 4, aQ);

            #pragma unroll
            for (int r = 0; r < 12; ++r) {
                float zx = aX[r];
                float a = vh[r], s = vs[r];
                float nx = s * zx;
                float t2 = 2.0f * a * nx;
                vx[r] = nx;
                vxx[r] = fmaf(-t2, zx, s * aQ[r]);
            }
        }
    }

    // ---- output layer ----
    float f = 0.f, ft = 0.f, fx = 0.f, fxx = 0.f;
    #pragma unroll
    for (int r = 0; r < 12; ++r) {
        float4 t = sIn4[hi * 16 + r];
        f   = fmaf(t.w, vh[r],  f);
        ft  = fmaf(t.w, vt[r],  ft);
        fx  = fmaf(t.w, vx[r],  fx);
        fxx = fmaf(t.w, vxx[r], fxx);
    }
    f   += __shfl_xor(f, 32);
    ft  += __shfl_xor(ft, 32);
    fx  += __shfl_xor(fx, 32);
    fxx += __shfl_xor(fxx, 32);
    f += bo;

    if (!hi) {
        const float pde = 0.5f * x1 * x1 + ft + 0.5f * fxx + 0.5f * x1 * fx
                          - 0.069444444444444f * fx * fx;
        out[P] = f;
        out[NPTS + P] = pde;
    }
}

extern "C" void kernel_launch(void* const* d_in, const int* in_sizes, int n_in,
                              void* d_out, int out_size, void* d_ws, size_t ws_size,
                              hipStream_t stream) {
    const float* x     = (const float*)d_in[0];
    const float* W_in  = (const float*)d_in[1];
    const float* b_in  = (const float*)d_in[2];
    const float* W_mid = (const float*)d_in[3];
    const float* b_mid = (const float*)d_in[4];
    const float* W_out = (const float*)d_in[5];
    const float* b_out = (const float*)d_in[6];
    float* out = (float*)d_out;

    hipLaunchKernelGGL(pde_mfma_kernel, dim3(NPTS / 128), dim3(256), 0, stream,
                       x, W_in, b_in, W_mid, b_mid, W_out, b_out, out);
}